// Round 4
// baseline (3769.116 us; speedup 1.0000x reference)
//
#include <hip/hip_runtime.h>
#include <math.h>

// ---------------------------------------------------------------------------
// RSSM: B=16, T=64 (bt=1024), encoder 3->32->64->128->256 (k4 s2 p1) with
// full-tensor LayerNorm+SiLU per layer, fc 4096->256, GRU(1030->128),
// prior 128->1024, post 384->1024, z = per-32-chunk argmax one-hot.
// All fp32: one flipped argmax = 1.0 error in z -> low precision in the
// logit path is fatal.
// R4 changes (from profile): gru_k was 1020us at VALUBusy=0.8% -- per-row
// weight reads put lanes 512B/1536B apart (64 cache lines per wave load).
// Fix: pre-transposed whhT[128][384], pwhT[128][1024] -> lane j reads
// wT[k*N+j] coalesced, h[k] LDS-broadcast. Argmax scan rotated to kill
// 32-way LDS bank conflicts (was 114K conflict cycles).
// ---------------------------------------------------------------------------

__device__ __forceinline__ float silu_f(float t){ return t / (1.f + __expf(-t)); }
__device__ __forceinline__ float sigm_f(float x){ return 1.f / (1.f + expf(-x)); }

// Block-level mean/rstd over m values; each thread contributes (s, s2).
__device__ __forceinline__ void block_stats_256(float s, float s2, int m,
                                                float& mean, float& rstd)
{
    __shared__ float red[8];
#pragma unroll
    for (int off = 32; off > 0; off >>= 1) {
        s  += __shfl_down(s, off);
        s2 += __shfl_down(s2, off);
    }
    int wv = threadIdx.x >> 6;
    if ((threadIdx.x & 63) == 0) { red[wv] = s; red[4 + wv] = s2; }
    __syncthreads();
    if (threadIdx.x == 0) {
        float S  = (red[0] + red[1]) + (red[2] + red[3]);
        float S2 = (red[4] + red[5]) + (red[6] + red[7]);
        float mu = S / m;
        float var = S2 / m - mu * mu;
        red[0] = mu;
        red[1] = rsqrtf(var + 1e-5f);
    }
    __syncthreads();
    mean = red[0]; rstd = red[1];
}

// ---------------- fused LayerNorm+SiLU, one block per sample ---------------
__global__ __launch_bounds__(256) void ln_fuse_k(float* __restrict__ x,
    const float* __restrict__ g, const float* __restrict__ b, int m)
{
    int n = blockIdx.x;
    float* p = x + (size_t)n * m;
    float s = 0.f, s2 = 0.f;
    for (int i = threadIdx.x * 4; i < m; i += 1024) {
        float4 v = *(const float4*)(p + i);
        s  += (v.x + v.y) + (v.z + v.w);
        s2 += (v.x*v.x + v.y*v.y) + (v.z*v.z + v.w*v.w);
    }
    float mean, rstd;
    block_stats_256(s, s2, m, mean, rstd);
    for (int i = threadIdx.x * 4; i < m; i += 1024) {
        float4 v  = *(float4*)(p + i);
        float4 gv = *(const float4*)(g + i);
        float4 bv = *(const float4*)(b + i);
        v.x = silu_f((v.x - mean) * rstd * gv.x + bv.x);
        v.y = silu_f((v.y - mean) * rstd * gv.y + bv.y);
        v.z = silu_f((v.z - mean) * rstd * gv.z + bv.z);
        v.w = silu_f((v.w - mean) * rstd * gv.w + bv.w);
        *(float4*)(p + i) = v;
    }
}

// ------------------------- conv1: 3x64x64 -> 32x32x32 ----------------------
__global__ __launch_bounds__(256) void conv1_k(const float* __restrict__ in,
    const float* __restrict__ w, const float* __restrict__ bias, float* __restrict__ out)
{
    int n  = blockIdx.x;                 // chunk-local sample
    int yq = blockIdx.y;                 // 4 y-quarters
    int tx = threadIdx.x & 31;
    int ty = threadIdx.x >> 5;           // 0..7
    int y  = yq * 8 + ty;                // 0..31
    const float* ip = in + (size_t)n * 12288;

    float okf[16]; int offs[16];
#pragma unroll
    for (int ky = 0; ky < 4; ky++) {
        int yy = 2 * y - 1 + ky;
        bool yok = ((unsigned)yy < 64u);
#pragma unroll
        for (int kx = 0; kx < 4; kx++) {
            int xx = 2 * tx - 1 + kx;
            bool ok = yok && ((unsigned)xx < 64u);
            okf[ky*4+kx]  = ok ? 1.f : 0.f;
            offs[ky*4+kx] = ok ? yy * 64 + xx : 0;
        }
    }
    float iv[48];
#pragma unroll
    for (int c = 0; c < 3; c++)
#pragma unroll
        for (int q = 0; q < 16; q++)
            iv[c*16+q] = ip[c*4096 + offs[q]] * okf[q];

    float* op = out + (size_t)n * 32768 + y * 32 + tx;
#pragma unroll 4
    for (int oc = 0; oc < 32; oc++) {           // oc uniform -> weights s_load
        float acc = bias[oc];
        const float* wp = w + oc * 48;
#pragma unroll
        for (int q = 0; q < 48; q++) acc += iv[q] * wp[q];
        op[oc * 1024] = acc;
    }
}

// ------------- conv2 raw: 32x32x32 -> 64x16x16, 4 oc-passes of 16 ----------
__global__ __launch_bounds__(256) void conv2_r(const float* __restrict__ in,
    const float* __restrict__ w, const float* __restrict__ bias, float* __restrict__ out)
{
    int n  = blockIdx.x;
    int tid = threadIdx.x;
    int tx = tid & 15, ty = tid >> 4;
    const float* ip = in + (size_t)n * 32768;

    float okf[16]; int offs[16];
#pragma unroll
    for (int ky = 0; ky < 4; ky++) {
        int yy = 2 * ty - 1 + ky;
        bool yok = ((unsigned)yy < 32u);
#pragma unroll
        for (int kx = 0; kx < 4; kx++) {
            int xx = 2 * tx - 1 + kx;
            bool ok = yok && ((unsigned)xx < 32u);
            okf[ky*4+kx]  = ok ? 1.f : 0.f;
            offs[ky*4+kx] = ok ? yy * 32 + xx : 0;
        }
    }
    float* op = out + (size_t)n * 16384 + tid;
#pragma unroll 1
    for (int p = 0; p < 4; p++) {
        float acc[16];
#pragma unroll
        for (int i = 0; i < 16; i++) acc[i] = bias[p * 16 + i];
        for (int c = 0; c < 32; c++) {
            const float* icp = ip + c * 1024;
            float iv[16];
#pragma unroll
            for (int q = 0; q < 16; q++) iv[q] = icp[offs[q]] * okf[q];
#pragma unroll
            for (int i = 0; i < 16; i++) {
                const float* wp = w + (size_t)p * 8192 + i * 512 + c * 16;  // uniform
#pragma unroll
                for (int q = 0; q < 16; q++) acc[i] += iv[q] * wp[q];
            }
        }
#pragma unroll
        for (int i = 0; i < 16; i++) op[(p * 16 + i) * 256] = acc[i];
    }
}

// ------------- conv3 raw: 64x16x16 -> 128x8x8, wave=32oc, 2 passes ---------
__global__ __launch_bounds__(256) void conv3_r(const float* __restrict__ in,
    const float* __restrict__ w, const float* __restrict__ bias, float* __restrict__ out)
{
    int n   = blockIdx.x;
    int tid = threadIdx.x;
    int ocq = __builtin_amdgcn_readfirstlane(tid >> 6);  // wave id 0..3
    int s0 = tid & 63, y = s0 >> 3, x = s0 & 7;
    const float* ip = in + (size_t)n * 16384;

    float okf[16]; int offs[16];
#pragma unroll
    for (int ky = 0; ky < 4; ky++) {
        int yy = 2 * y - 1 + ky;
        bool yok = ((unsigned)yy < 16u);
#pragma unroll
        for (int kx = 0; kx < 4; kx++) {
            int xx = 2 * x - 1 + kx;
            bool ok = yok && ((unsigned)xx < 16u);
            okf[ky*4+kx]  = ok ? 1.f : 0.f;
            offs[ky*4+kx] = ok ? yy * 16 + xx : 0;
        }
    }
    float* op = out + (size_t)n * 8192 + s0;
#pragma unroll 1
    for (int p = 0; p < 2; p++) {
        int ocb = ocq * 32 + p * 16;                     // wave-uniform
        float acc[16];
#pragma unroll
        for (int i = 0; i < 16; i++) acc[i] = bias[ocb + i];
        for (int c = 0; c < 64; c++) {
            const float* icp = ip + c * 256;
            float iv[16];
#pragma unroll
            for (int q = 0; q < 16; q++) iv[q] = icp[offs[q]] * okf[q];
#pragma unroll
            for (int i = 0; i < 16; i++) {
                const float* wp = w + ((size_t)(ocb + i) * 64 + c) * 16;  // wave-uniform
#pragma unroll
                for (int q = 0; q < 16; q++) acc[i] += iv[q] * wp[q];
            }
        }
#pragma unroll
        for (int i = 0; i < 16; i++) op[(ocb + i) * 64] = acc[i];
    }
}

// ----------------- conv4 + LN4 + SiLU: 128x8x8 -> 256x4x4 ------------------
__global__ __launch_bounds__(256) void conv4_f(const float* __restrict__ in,
    const float* __restrict__ w, const float* __restrict__ bias,
    const float* __restrict__ g, const float* __restrict__ bet, float* __restrict__ out)
{
    int n  = blockIdx.x;
    int oc = threadIdx.x;                 // 0..255
    const float* ip = in + (size_t)n * 8192;
    const float* wr = w + (size_t)oc * 2048;

    float acc[16];
#pragma unroll
    for (int s = 0; s < 16; s++) acc[s] = bias[oc];

    for (int c = 0; c < 128; c++) {
        const float* ic = ip + c * 64;     // uniform base -> s_load, CSE'd
        const float* wc = wr + c * 16;
        float wf[16];
#pragma unroll
        for (int q = 0; q < 16; q += 4) {
            float4 v = *(const float4*)(wc + q);
            wf[q] = v.x; wf[q+1] = v.y; wf[q+2] = v.z; wf[q+3] = v.w;
        }
#pragma unroll
        for (int y = 0; y < 4; y++)
#pragma unroll
        for (int x = 0; x < 4; x++) {
            float a = acc[y * 4 + x];
#pragma unroll
            for (int ky = 0; ky < 4; ky++) {
                int yy = 2 * y - 1 + ky;
                if (yy < 0 || yy > 7) continue;      // folds at compile time
#pragma unroll
                for (int kx = 0; kx < 4; kx++) {
                    int xx = 2 * x - 1 + kx;
                    if (xx < 0 || xx > 7) continue;
                    a += wf[ky * 4 + kx] * ic[yy * 8 + xx];
                }
            }
            acc[y * 4 + x] = a;
        }
    }
    float s = 0.f, s2 = 0.f;
#pragma unroll
    for (int q = 0; q < 16; q++) { s += acc[q]; s2 += acc[q] * acc[q]; }
    float mean, rstd;
    block_stats_256(s, s2, 4096, mean, rstd);

    float* op = out + (size_t)n * 4096;
#pragma unroll
    for (int q = 0; q < 16; q++) {
        int flat = oc * 16 + q;
        float v = (acc[q] - mean) * rstd * g[flat] + bet[flat];
        op[flat] = silu_f(v);
    }
}

// -------- transpose fc_w [256][4096] -> fcwT [4096][256] (LDS-tiled) -------
__global__ __launch_bounds__(256) void trfc_k(const float* __restrict__ w,
                                              float* __restrict__ wt)
{
    __shared__ float t[32][33];
    int bk = blockIdx.x * 32;             // k dim (4096)
    int bj = blockIdx.y * 32;             // j dim (256)
    int lx = threadIdx.x & 31, ly = threadIdx.x >> 5;   // 32 x 8
#pragma unroll
    for (int s = 0; s < 4; s++)
        t[ly + 8*s][lx] = w[(size_t)(bj + ly + 8*s) * 4096 + bk + lx];
    __syncthreads();
#pragma unroll
    for (int s = 0; s < 4; s++)
        wt[(size_t)(bk + ly + 8*s) * 256 + bj + lx] = t[lx][ly + 8*s];
}

// ---------------- fc: [S,4096] @ wT[4096][256], coalesced ------------------
__global__ __launch_bounds__(256) void fc_k2(const float* __restrict__ a,
    const float* __restrict__ wT, const float* __restrict__ bias, float* __restrict__ o)
{
    int n0 = blockIdx.x * 8;              // chunk-local rows
    int j  = threadIdx.x;
    float acc[8];
#pragma unroll
    for (int r = 0; r < 8; r++) acc[r] = 0.f;
    for (int k = 0; k < 4096; k += 4) {
        float wv0 = wT[(size_t)k * 256 + j];
        float wv1 = wT[(size_t)(k+1) * 256 + j];
        float wv2 = wT[(size_t)(k+2) * 256 + j];
        float wv3 = wT[(size_t)(k+3) * 256 + j];
#pragma unroll
        for (int r = 0; r < 8; r++) {
            const float* ar = a + (size_t)(n0 + r) * 4096 + k;   // uniform -> s_load x4
            acc[r] += wv0*ar[0] + wv1*ar[1] + wv2*ar[2] + wv3*ar[3];
        }
    }
    float bj = bias[j];
#pragma unroll
    for (int r = 0; r < 8; r++) o[(size_t)(n0 + r) * 256 + j] = acc[r] + bj;
}

// ----------- Fpost[n,j] = post_b[j] + feats[n,:] @ post_w[j,128:384] -------
__global__ __launch_bounds__(256) void fpost_k(const float* __restrict__ f,
    const float* __restrict__ w, const float* __restrict__ bias, float* __restrict__ o)
{
    int n0 = blockIdx.x * 4;
    int tid = threadIdx.x;
    float acc[4][4];
#pragma unroll
    for (int r = 0; r < 4; r++)
#pragma unroll
        for (int jj = 0; jj < 4; jj++) acc[r][jj] = 0.f;
    for (int k = 0; k < 256; k += 4) {
        float4 wv[4];
#pragma unroll
        for (int jj = 0; jj < 4; jj++)
            wv[jj] = *(const float4*)(w + (size_t)(tid + jj * 256) * 384 + 128 + k);
#pragma unroll
        for (int r = 0; r < 4; r++) {
            const float* fr = f + (size_t)(n0 + r) * 256 + k;    // uniform
            float a0 = fr[0], a1 = fr[1], a2 = fr[2], a3 = fr[3];
#pragma unroll
            for (int jj = 0; jj < 4; jj++)
                acc[r][jj] += wv[jj].x*a0 + wv[jj].y*a1 + wv[jj].z*a2 + wv[jj].w*a3;
        }
    }
#pragma unroll
    for (int jj = 0; jj < 4; jj++) {
        float bj = bias[tid + jj * 256];
#pragma unroll
        for (int r = 0; r < 4; r++)
            o[(size_t)(n0 + r) * 1024 + tid + jj * 256] = acc[r][jj] + bj;
    }
}

// ----------- prior[n,j] = prior_b[j] + h[n,:] @ prior_w[j,:] ---------------
__global__ __launch_bounds__(256) void prior_k(const float* __restrict__ h,
    const float* __restrict__ w, const float* __restrict__ bias, float* __restrict__ o)
{
    int n0 = blockIdx.x * 4;
    int tid = threadIdx.x;
    float acc[4][4];
#pragma unroll
    for (int r = 0; r < 4; r++)
#pragma unroll
        for (int jj = 0; jj < 4; jj++) acc[r][jj] = 0.f;
    for (int k = 0; k < 128; k += 4) {
        float4 wv[4];
#pragma unroll
        for (int jj = 0; jj < 4; jj++)
            wv[jj] = *(const float4*)(w + (size_t)(tid + jj * 256) * 128 + k);
#pragma unroll
        for (int r = 0; r < 4; r++) {
            const float* hr = h + (size_t)(n0 + r) * 128 + k;    // uniform
            float a0 = hr[0], a1 = hr[1], a2 = hr[2], a3 = hr[3];
#pragma unroll
            for (int jj = 0; jj < 4; jj++)
                acc[r][jj] += wv[jj].x*a0 + wv[jj].y*a1 + wv[jj].z*a2 + wv[jj].w*a3;
        }
    }
#pragma unroll
    for (int jj = 0; jj < 4; jj++) {
        float bj = bias[tid + jj * 256];
#pragma unroll
        for (int r = 0; r < 4; r++)
            o[(size_t)(n0 + r) * 1024 + tid + jj * 256] = acc[r][jj] + bj;
    }
}

// ----------- Ai[n,j] = bih[j] + actions[n,:] @ wih[j,1024:1030] ------------
__global__ __launch_bounds__(128) void ai_k(const float* __restrict__ act,
    const float* __restrict__ wih, const float* __restrict__ bih, float* __restrict__ o)
{
    int n = blockIdx.x;
    int j = blockIdx.y * 128 + threadIdx.x;     // 0..383
    const float* ar = act + (size_t)n * 6;       // uniform
    const float* wr = wih + (size_t)j * 1030 + 1024;
    float acc = bih[j];
#pragma unroll
    for (int k = 0; k < 6; k++) acc += ar[k] * wr[k];
    o[(size_t)n * 384 + j] = acc;
}

// ----------- wihT[k,j] = wih[j,k]  (z-part only, k<1024) -------------------
__global__ __launch_bounds__(256) void tr_k(const float* __restrict__ wih,
                                            float* __restrict__ wt)
{
    int g = blockIdx.x * 256 + threadIdx.x;      // 0..393215
    int k = g / 384;
    int j = g - k * 384;
    wt[g] = wih[(size_t)j * 1030 + k];
}

// ----------- whhT[k,j] = whh[j,k]  (128 x 384) -----------------------------
__global__ __launch_bounds__(256) void tr2_k(const float* __restrict__ whh,
                                             float* __restrict__ wt)
{
    int g = blockIdx.x * 256 + threadIdx.x;      // 0..49151
    int k = g / 384;
    int j = g - k * 384;
    wt[g] = whh[(size_t)j * 128 + k];
}

// ----------- pwhT[k,j] = post_w[j,k]  (128 x 1024, h-part) -----------------
__global__ __launch_bounds__(256) void trpw_k(const float* __restrict__ pw,
                                              float* __restrict__ wt)
{
    int g = blockIdx.x * 256 + threadIdx.x;      // 0..131071
    int k = g >> 10;
    int j = g & 1023;
    wt[g] = pw[(size_t)j * 384 + k];
}

// ------------------------- GRU recurrence (1 block / sample) ---------------
// All weight reads coalesced via transposed layouts; h broadcast from LDS.
__global__ __launch_bounds__(1024) void gru_k(const float* __restrict__ wihT,
    const float* __restrict__ whhT, const float* __restrict__ bhh,
    const float* __restrict__ ai, const float* __restrict__ fpost,
    const float* __restrict__ pwhT, float* __restrict__ out)
{
    float* out_post = out + 1048576;
    float* out_h    = out + 2097152;
    float* out_z    = out + 2228224;
    int b   = blockIdx.x;
    int tid = threadIdx.x;
    __shared__ __align__(16) float h[128];
    __shared__ float gi[384], gh[384], p[1024];
    __shared__ int idx[32];
    if (tid < 128) h[tid] = 0.f;
    __syncthreads();

    for (int t = 0; t < 64; t++) {
        int n = b * 64 + t;
        if (tid < 384) {
            float a = ai[(size_t)n * 384 + tid];
            if (t > 0) {
#pragma unroll 8
                for (int c = 0; c < 32; c++)
                    a += wihT[(size_t)(c * 32 + idx[c]) * 384 + tid];   // coalesced
            }
            gi[tid] = a;
            float a2 = bhh[tid];
#pragma unroll 8
            for (int k = 0; k < 128; k += 4) {
                float4 hv = *(const float4*)(h + k);                    // broadcast
                a2 += whhT[(size_t)(k+0) * 384 + tid] * hv.x            // coalesced
                    + whhT[(size_t)(k+1) * 384 + tid] * hv.y
                    + whhT[(size_t)(k+2) * 384 + tid] * hv.z
                    + whhT[(size_t)(k+3) * 384 + tid] * hv.w;
            }
            gh[tid] = a2;
        }
        __syncthreads();                                    // B1
        if (tid < 128) {
            float r  = sigm_f(gi[tid] + gh[tid]);
            float u  = sigm_f(gi[128 + tid] + gh[128 + tid]);
            float nn = tanhf(gi[256 + tid] + r * gh[256 + tid]);
            float hn = (1.f - u) * nn + u * h[tid];
            h[tid] = hn;
            out_h[(size_t)n * 128 + tid] = hn;
        }
        __syncthreads();                                    // B2
        {
            float a = fpost[(size_t)n * 1024 + tid];
#pragma unroll 8
            for (int k = 0; k < 128; k += 4) {
                float4 hv = *(const float4*)(h + k);                    // broadcast
                a += pwhT[(size_t)(k+0) * 1024 + tid] * hv.x            // coalesced
                   + pwhT[(size_t)(k+1) * 1024 + tid] * hv.y
                   + pwhT[(size_t)(k+2) * 1024 + tid] * hv.z
                   + pwhT[(size_t)(k+3) * 1024 + tid] * hv.w;
            }
            p[tid] = a;
            out_post[(size_t)n * 1024 + tid] = a;
        }
        __syncthreads();                                    // B3
        if (tid < 32) {
            // rotated scan: thread t reads p[t*32 + (q+t)&31] -> conflict-free.
            // first-max semantics = min index among maxima.
            const float* pc = p + tid * 32;
            int qq0 = tid & 31;
            float best = pc[qq0]; int bi = qq0;
#pragma unroll
            for (int q = 1; q < 32; q++) {
                int qq = (q + tid) & 31;
                float v = pc[qq];
                if (v > best || (v == best && qq < bi)) { best = v; bi = qq; }
            }
            idx[tid] = bi;
        }
        __syncthreads();                                    // B4
        out_z[(size_t)n * 1024 + tid] = ((tid & 31) == idx[tid >> 5]) ? 1.f : 0.f;
    }
}

// ---------------------------------------------------------------------------
extern "C" void kernel_launch(void* const* d_in, const int* in_sizes, int n_in,
                              void* d_out, int out_size, void* d_ws, size_t ws_size,
                              hipStream_t stream)
{
    const float* states  = (const float*)d_in[0];
    const float* actions = (const float*)d_in[1];
    const float* c1w = (const float*)d_in[2];  const float* c1b = (const float*)d_in[3];
    const float* l1g = (const float*)d_in[4];  const float* l1b = (const float*)d_in[5];
    const float* c2w = (const float*)d_in[6];  const float* c2b = (const float*)d_in[7];
    const float* l2g = (const float*)d_in[8];  const float* l2b = (const float*)d_in[9];
    const float* c3w = (const float*)d_in[10]; const float* c3b = (const float*)d_in[11];
    const float* l3g = (const float*)d_in[12]; const float* l3b = (const float*)d_in[13];
    const float* c4w = (const float*)d_in[14]; const float* c4b = (const float*)d_in[15];
    const float* l4g = (const float*)d_in[16]; const float* l4b = (const float*)d_in[17];
    const float* fcw = (const float*)d_in[18]; const float* fcb = (const float*)d_in[19];
    const float* wih = (const float*)d_in[20]; const float* whh = (const float*)d_in[21];
    const float* bih = (const float*)d_in[22]; const float* bhh = (const float*)d_in[23];
    const float* prw = (const float*)d_in[24]; const float* prb = (const float*)d_in[25];
    const float* pw  = (const float*)d_in[26]; const float* pb  = (const float*)d_in[27];

    float* out = (float*)d_out;
    float* ws  = (float*)d_ws;

    // ---- adaptive chunking: largest S whose footprint fits ws_size --------
    // footprint = (S*49152 + fixed 3,325,952) floats
    size_t S = 64;
    {
        const size_t cands[4] = {1024, 512, 256, 128};
        for (int i = 0; i < 4; i++) {
            size_t need = (cands[i] * 49152ull + 3325952ull) * 4ull;
            if (need <= ws_size) { S = cands[i]; break; }
        }
    }
    int C = (int)(1024 / S);

    float* bufA  = ws;                       // S*32768
    float* bufB  = bufA + S * 32768;         // S*16384
    float* feats = bufB + S * 16384;         //   262,144
    float* fpost = feats + 262144;           // 1,048,576
    float* aibuf = fpost + 1048576;          //   393,216
    float* wihT  = aibuf + 393216;           //   393,216
    float* fcwT  = wihT + 393216;            // 1,048,576
    float* whhT  = fcwT + 1048576;           //    49,152
    float* pwhT  = whhT + 49152;             //   131,072

    trfc_k<<<dim3(128, 8), 256, 0, stream>>>(fcw, fcwT);

    for (int cc = 0; cc < C; cc++) {
        size_t n0 = (size_t)cc * S;
        conv1_k<<<dim3((unsigned)S, 4), 256, 0, stream>>>(states + n0 * 12288, c1w, c1b, bufA);
        ln_fuse_k<<<(unsigned)S, 256, 0, stream>>>(bufA, l1g, l1b, 32768);
        conv2_r<<<(unsigned)S, 256, 0, stream>>>(bufA, c2w, c2b, bufB);
        ln_fuse_k<<<(unsigned)S, 256, 0, stream>>>(bufB, l2g, l2b, 16384);
        conv3_r<<<(unsigned)S, 256, 0, stream>>>(bufB, c3w, c3b, bufA);
        ln_fuse_k<<<(unsigned)S, 256, 0, stream>>>(bufA, l3g, l3b, 8192);
        conv4_f<<<(unsigned)S, 256, 0, stream>>>(bufA, c4w, c4b, l4g, l4b, bufB);
        fc_k2<<<(unsigned)(S / 8), 256, 0, stream>>>(bufB, fcwT, fcb, feats + n0 * 256);
    }

    fpost_k<<<256, 256, 0, stream>>>(feats, pw, pb, fpost);
    ai_k<<<dim3(1024, 3), 128, 0, stream>>>(actions, wih, bih, aibuf);
    tr_k<<<1536, 256, 0, stream>>>(wih, wihT);
    tr2_k<<<192, 256, 0, stream>>>(whh, whhT);
    trpw_k<<<512, 256, 0, stream>>>(pw, pwhT);

    gru_k<<<16, 1024, 0, stream>>>(wihT, whhT, bhh, aibuf, fpost, pwhT, out);
    prior_k<<<256, 256, 0, stream>>>(out + 2097152, prw, prb, out);
}

// Round 5
// 3689.401 us; speedup vs baseline: 1.0216x; 1.0216x over previous
//
#include <hip/hip_runtime.h>
#include <math.h>

// ---------------------------------------------------------------------------
// RSSM: B=16, T=64 (bt=1024), encoder 3->32->64->128->256 (k4 s2 p1) with
// full-tensor LayerNorm+SiLU per layer, fc 4096->256, GRU(1030->128),
// prior 128->1024, post 384->1024, z = per-32-chunk argmax one-hot.
// All fp32: one flipped argmax = 1.0 error in z -> low precision in the
// logit path is fatal.
// R5 changes (from profile): R4's coalesced gru_k got SLOWER (1123us,
// VALUBusy 1.4%) -> bottleneck is per-step L2 latency re-streaming 770KB of
// step-invariant weights. Fix: weights live in REGISTERS across the t-loop
// (pwh[128]/thread, whr[128] for tid<384; ~256 VGPRs, fine at 4 waves/SIMD
// with __launch_bounds__(1024,1)). Per-step matvecs = FMA + LDS-broadcast h,
// zero global weight loads. Argmax via 32-lane shfl butterfly (first-max
// tie-break), no LDS scan, 3 barriers/step.
// ---------------------------------------------------------------------------

__device__ __forceinline__ float silu_f(float t){ return t / (1.f + __expf(-t)); }
__device__ __forceinline__ float sigm_f(float x){ return 1.f / (1.f + expf(-x)); }

// Block-level mean/rstd over m values; each thread contributes (s, s2).
__device__ __forceinline__ void block_stats_256(float s, float s2, int m,
                                                float& mean, float& rstd)
{
    __shared__ float red[8];
#pragma unroll
    for (int off = 32; off > 0; off >>= 1) {
        s  += __shfl_down(s, off);
        s2 += __shfl_down(s2, off);
    }
    int wv = threadIdx.x >> 6;
    if ((threadIdx.x & 63) == 0) { red[wv] = s; red[4 + wv] = s2; }
    __syncthreads();
    if (threadIdx.x == 0) {
        float S  = (red[0] + red[1]) + (red[2] + red[3]);
        float S2 = (red[4] + red[5]) + (red[6] + red[7]);
        float mu = S / m;
        float var = S2 / m - mu * mu;
        red[0] = mu;
        red[1] = rsqrtf(var + 1e-5f);
    }
    __syncthreads();
    mean = red[0]; rstd = red[1];
}

// ---------------- fused LayerNorm+SiLU, one block per sample ---------------
__global__ __launch_bounds__(256) void ln_fuse_k(float* __restrict__ x,
    const float* __restrict__ g, const float* __restrict__ b, int m)
{
    int n = blockIdx.x;
    float* p = x + (size_t)n * m;
    float s = 0.f, s2 = 0.f;
    for (int i = threadIdx.x * 4; i < m; i += 1024) {
        float4 v = *(const float4*)(p + i);
        s  += (v.x + v.y) + (v.z + v.w);
        s2 += (v.x*v.x + v.y*v.y) + (v.z*v.z + v.w*v.w);
    }
    float mean, rstd;
    block_stats_256(s, s2, m, mean, rstd);
    for (int i = threadIdx.x * 4; i < m; i += 1024) {
        float4 v  = *(float4*)(p + i);
        float4 gv = *(const float4*)(g + i);
        float4 bv = *(const float4*)(b + i);
        v.x = silu_f((v.x - mean) * rstd * gv.x + bv.x);
        v.y = silu_f((v.y - mean) * rstd * gv.y + bv.y);
        v.z = silu_f((v.z - mean) * rstd * gv.z + bv.z);
        v.w = silu_f((v.w - mean) * rstd * gv.w + bv.w);
        *(float4*)(p + i) = v;
    }
}

// ------------------------- conv1: 3x64x64 -> 32x32x32 ----------------------
__global__ __launch_bounds__(256) void conv1_k(const float* __restrict__ in,
    const float* __restrict__ w, const float* __restrict__ bias, float* __restrict__ out)
{
    int n  = blockIdx.x;                 // chunk-local sample
    int yq = blockIdx.y;                 // 4 y-quarters
    int tx = threadIdx.x & 31;
    int ty = threadIdx.x >> 5;           // 0..7
    int y  = yq * 8 + ty;                // 0..31
    const float* ip = in + (size_t)n * 12288;

    float okf[16]; int offs[16];
#pragma unroll
    for (int ky = 0; ky < 4; ky++) {
        int yy = 2 * y - 1 + ky;
        bool yok = ((unsigned)yy < 64u);
#pragma unroll
        for (int kx = 0; kx < 4; kx++) {
            int xx = 2 * tx - 1 + kx;
            bool ok = yok && ((unsigned)xx < 64u);
            okf[ky*4+kx]  = ok ? 1.f : 0.f;
            offs[ky*4+kx] = ok ? yy * 64 + xx : 0;
        }
    }
    float iv[48];
#pragma unroll
    for (int c = 0; c < 3; c++)
#pragma unroll
        for (int q = 0; q < 16; q++)
            iv[c*16+q] = ip[c*4096 + offs[q]] * okf[q];

    float* op = out + (size_t)n * 32768 + y * 32 + tx;
#pragma unroll 4
    for (int oc = 0; oc < 32; oc++) {           // oc uniform -> weights s_load
        float acc = bias[oc];
        const float* wp = w + oc * 48;
#pragma unroll
        for (int q = 0; q < 48; q++) acc += iv[q] * wp[q];
        op[oc * 1024] = acc;
    }
}

// ------------- conv2 raw: 32x32x32 -> 64x16x16, 4 oc-passes of 16 ----------
__global__ __launch_bounds__(256) void conv2_r(const float* __restrict__ in,
    const float* __restrict__ w, const float* __restrict__ bias, float* __restrict__ out)
{
    int n  = blockIdx.x;
    int tid = threadIdx.x;
    int tx = tid & 15, ty = tid >> 4;
    const float* ip = in + (size_t)n * 32768;

    float okf[16]; int offs[16];
#pragma unroll
    for (int ky = 0; ky < 4; ky++) {
        int yy = 2 * ty - 1 + ky;
        bool yok = ((unsigned)yy < 32u);
#pragma unroll
        for (int kx = 0; kx < 4; kx++) {
            int xx = 2 * tx - 1 + kx;
            bool ok = yok && ((unsigned)xx < 32u);
            okf[ky*4+kx]  = ok ? 1.f : 0.f;
            offs[ky*4+kx] = ok ? yy * 32 + xx : 0;
        }
    }
    float* op = out + (size_t)n * 16384 + tid;
#pragma unroll 1
    for (int p = 0; p < 4; p++) {
        float acc[16];
#pragma unroll
        for (int i = 0; i < 16; i++) acc[i] = bias[p * 16 + i];
        for (int c = 0; c < 32; c++) {
            const float* icp = ip + c * 1024;
            float iv[16];
#pragma unroll
            for (int q = 0; q < 16; q++) iv[q] = icp[offs[q]] * okf[q];
#pragma unroll
            for (int i = 0; i < 16; i++) {
                const float* wp = w + (size_t)p * 8192 + i * 512 + c * 16;  // uniform
#pragma unroll
                for (int q = 0; q < 16; q++) acc[i] += iv[q] * wp[q];
            }
        }
#pragma unroll
        for (int i = 0; i < 16; i++) op[(p * 16 + i) * 256] = acc[i];
    }
}

// ------------- conv3 raw: 64x16x16 -> 128x8x8, wave=32oc, 2 passes ---------
__global__ __launch_bounds__(256) void conv3_r(const float* __restrict__ in,
    const float* __restrict__ w, const float* __restrict__ bias, float* __restrict__ out)
{
    int n   = blockIdx.x;
    int tid = threadIdx.x;
    int ocq = __builtin_amdgcn_readfirstlane(tid >> 6);  // wave id 0..3
    int s0 = tid & 63, y = s0 >> 3, x = s0 & 7;
    const float* ip = in + (size_t)n * 16384;

    float okf[16]; int offs[16];
#pragma unroll
    for (int ky = 0; ky < 4; ky++) {
        int yy = 2 * y - 1 + ky;
        bool yok = ((unsigned)yy < 16u);
#pragma unroll
        for (int kx = 0; kx < 4; kx++) {
            int xx = 2 * x - 1 + kx;
            bool ok = yok && ((unsigned)xx < 16u);
            okf[ky*4+kx]  = ok ? 1.f : 0.f;
            offs[ky*4+kx] = ok ? yy * 16 + xx : 0;
        }
    }
    float* op = out + (size_t)n * 8192 + s0;
#pragma unroll 1
    for (int p = 0; p < 2; p++) {
        int ocb = ocq * 32 + p * 16;                     // wave-uniform
        float acc[16];
#pragma unroll
        for (int i = 0; i < 16; i++) acc[i] = bias[ocb + i];
        for (int c = 0; c < 64; c++) {
            const float* icp = ip + c * 256;
            float iv[16];
#pragma unroll
            for (int q = 0; q < 16; q++) iv[q] = icp[offs[q]] * okf[q];
#pragma unroll
            for (int i = 0; i < 16; i++) {
                const float* wp = w + ((size_t)(ocb + i) * 64 + c) * 16;  // wave-uniform
#pragma unroll
                for (int q = 0; q < 16; q++) acc[i] += iv[q] * wp[q];
            }
        }
#pragma unroll
        for (int i = 0; i < 16; i++) op[(ocb + i) * 64] = acc[i];
    }
}

// ----------------- conv4 + LN4 + SiLU: 128x8x8 -> 256x4x4 ------------------
__global__ __launch_bounds__(256) void conv4_f(const float* __restrict__ in,
    const float* __restrict__ w, const float* __restrict__ bias,
    const float* __restrict__ g, const float* __restrict__ bet, float* __restrict__ out)
{
    int n  = blockIdx.x;
    int oc = threadIdx.x;                 // 0..255
    const float* ip = in + (size_t)n * 8192;
    const float* wr = w + (size_t)oc * 2048;

    float acc[16];
#pragma unroll
    for (int s = 0; s < 16; s++) acc[s] = bias[oc];

    for (int c = 0; c < 128; c++) {
        const float* ic = ip + c * 64;     // uniform base -> s_load, CSE'd
        const float* wc = wr + c * 16;
        float wf[16];
#pragma unroll
        for (int q = 0; q < 16; q += 4) {
            float4 v = *(const float4*)(wc + q);
            wf[q] = v.x; wf[q+1] = v.y; wf[q+2] = v.z; wf[q+3] = v.w;
        }
#pragma unroll
        for (int y = 0; y < 4; y++)
#pragma unroll
        for (int x = 0; x < 4; x++) {
            float a = acc[y * 4 + x];
#pragma unroll
            for (int ky = 0; ky < 4; ky++) {
                int yy = 2 * y - 1 + ky;
                if (yy < 0 || yy > 7) continue;      // folds at compile time
#pragma unroll
                for (int kx = 0; kx < 4; kx++) {
                    int xx = 2 * x - 1 + kx;
                    if (xx < 0 || xx > 7) continue;
                    a += wf[ky * 4 + kx] * ic[yy * 8 + xx];
                }
            }
            acc[y * 4 + x] = a;
        }
    }
    float s = 0.f, s2 = 0.f;
#pragma unroll
    for (int q = 0; q < 16; q++) { s += acc[q]; s2 += acc[q] * acc[q]; }
    float mean, rstd;
    block_stats_256(s, s2, 4096, mean, rstd);

    float* op = out + (size_t)n * 4096;
#pragma unroll
    for (int q = 0; q < 16; q++) {
        int flat = oc * 16 + q;
        float v = (acc[q] - mean) * rstd * g[flat] + bet[flat];
        op[flat] = silu_f(v);
    }
}

// -------- transpose fc_w [256][4096] -> fcwT [4096][256] (LDS-tiled) -------
__global__ __launch_bounds__(256) void trfc_k(const float* __restrict__ w,
                                              float* __restrict__ wt)
{
    __shared__ float t[32][33];
    int bk = blockIdx.x * 32;             // k dim (4096)
    int bj = blockIdx.y * 32;             // j dim (256)
    int lx = threadIdx.x & 31, ly = threadIdx.x >> 5;   // 32 x 8
#pragma unroll
    for (int s = 0; s < 4; s++)
        t[ly + 8*s][lx] = w[(size_t)(bj + ly + 8*s) * 4096 + bk + lx];
    __syncthreads();
#pragma unroll
    for (int s = 0; s < 4; s++)
        wt[(size_t)(bk + ly + 8*s) * 256 + bj + lx] = t[lx][ly + 8*s];
}

// ---------------- fc: [S,4096] @ wT[4096][256], coalesced ------------------
__global__ __launch_bounds__(256) void fc_k2(const float* __restrict__ a,
    const float* __restrict__ wT, const float* __restrict__ bias, float* __restrict__ o)
{
    int n0 = blockIdx.x * 8;              // chunk-local rows
    int j  = threadIdx.x;
    float acc[8];
#pragma unroll
    for (int r = 0; r < 8; r++) acc[r] = 0.f;
    for (int k = 0; k < 4096; k += 4) {
        float wv0 = wT[(size_t)k * 256 + j];
        float wv1 = wT[(size_t)(k+1) * 256 + j];
        float wv2 = wT[(size_t)(k+2) * 256 + j];
        float wv3 = wT[(size_t)(k+3) * 256 + j];
#pragma unroll
        for (int r = 0; r < 8; r++) {
            const float* ar = a + (size_t)(n0 + r) * 4096 + k;   // uniform -> s_load x4
            acc[r] += wv0*ar[0] + wv1*ar[1] + wv2*ar[2] + wv3*ar[3];
        }
    }
    float bj = bias[j];
#pragma unroll
    for (int r = 0; r < 8; r++) o[(size_t)(n0 + r) * 256 + j] = acc[r] + bj;
}

// ----------- Fpost[n,j] = post_b[j] + feats[n,:] @ post_w[j,128:384] -------
__global__ __launch_bounds__(256) void fpost_k(const float* __restrict__ f,
    const float* __restrict__ w, const float* __restrict__ bias, float* __restrict__ o)
{
    int n0 = blockIdx.x * 4;
    int tid = threadIdx.x;
    float acc[4][4];
#pragma unroll
    for (int r = 0; r < 4; r++)
#pragma unroll
        for (int jj = 0; jj < 4; jj++) acc[r][jj] = 0.f;
    for (int k = 0; k < 256; k += 4) {
        float4 wv[4];
#pragma unroll
        for (int jj = 0; jj < 4; jj++)
            wv[jj] = *(const float4*)(w + (size_t)(tid + jj * 256) * 384 + 128 + k);
#pragma unroll
        for (int r = 0; r < 4; r++) {
            const float* fr = f + (size_t)(n0 + r) * 256 + k;    // uniform
            float a0 = fr[0], a1 = fr[1], a2 = fr[2], a3 = fr[3];
#pragma unroll
            for (int jj = 0; jj < 4; jj++)
                acc[r][jj] += wv[jj].x*a0 + wv[jj].y*a1 + wv[jj].z*a2 + wv[jj].w*a3;
        }
    }
#pragma unroll
    for (int jj = 0; jj < 4; jj++) {
        float bj = bias[tid + jj * 256];
#pragma unroll
        for (int r = 0; r < 4; r++)
            o[(size_t)(n0 + r) * 1024 + tid + jj * 256] = acc[r][jj] + bj;
    }
}

// ----------- prior[n,j] = prior_b[j] + h[n,:] @ prior_w[j,:] ---------------
__global__ __launch_bounds__(256) void prior_k(const float* __restrict__ h,
    const float* __restrict__ w, const float* __restrict__ bias, float* __restrict__ o)
{
    int n0 = blockIdx.x * 4;
    int tid = threadIdx.x;
    float acc[4][4];
#pragma unroll
    for (int r = 0; r < 4; r++)
#pragma unroll
        for (int jj = 0; jj < 4; jj++) acc[r][jj] = 0.f;
    for (int k = 0; k < 128; k += 4) {
        float4 wv[4];
#pragma unroll
        for (int jj = 0; jj < 4; jj++)
            wv[jj] = *(const float4*)(w + (size_t)(tid + jj * 256) * 128 + k);
#pragma unroll
        for (int r = 0; r < 4; r++) {
            const float* hr = h + (size_t)(n0 + r) * 128 + k;    // uniform
            float a0 = hr[0], a1 = hr[1], a2 = hr[2], a3 = hr[3];
#pragma unroll
            for (int jj = 0; jj < 4; jj++)
                acc[r][jj] += wv[jj].x*a0 + wv[jj].y*a1 + wv[jj].z*a2 + wv[jj].w*a3;
        }
    }
#pragma unroll
    for (int jj = 0; jj < 4; jj++) {
        float bj = bias[tid + jj * 256];
#pragma unroll
        for (int r = 0; r < 4; r++)
            o[(size_t)(n0 + r) * 1024 + tid + jj * 256] = acc[r][jj] + bj;
    }
}

// ----------- Ai[n,j] = bih[j] + actions[n,:] @ wih[j,1024:1030] ------------
__global__ __launch_bounds__(128) void ai_k(const float* __restrict__ act,
    const float* __restrict__ wih, const float* __restrict__ bih, float* __restrict__ o)
{
    int n = blockIdx.x;
    int j = blockIdx.y * 128 + threadIdx.x;     // 0..383
    const float* ar = act + (size_t)n * 6;       // uniform
    const float* wr = wih + (size_t)j * 1030 + 1024;
    float acc = bih[j];
#pragma unroll
    for (int k = 0; k < 6; k++) acc += ar[k] * wr[k];
    o[(size_t)n * 384 + j] = acc;
}

// ----------- wihT[k,j] = wih[j,k]  (z-part only, k<1024) -------------------
__global__ __launch_bounds__(256) void tr_k(const float* __restrict__ wih,
                                            float* __restrict__ wt)
{
    int g = blockIdx.x * 256 + threadIdx.x;      // 0..393215
    int k = g / 384;
    int j = g - k * 384;
    wt[g] = wih[(size_t)j * 1030 + k];
}

// ----------- whhT[k,j] = whh[j,k]  (128 x 384) -----------------------------
__global__ __launch_bounds__(256) void tr2_k(const float* __restrict__ whh,
                                             float* __restrict__ wt)
{
    int g = blockIdx.x * 256 + threadIdx.x;      // 0..49151
    int k = g / 384;
    int j = g - k * 384;
    wt[g] = whh[(size_t)j * 128 + k];
}

// ----------- pwhT[k,j] = post_w[j,k]  (128 x 1024, h-part) -----------------
__global__ __launch_bounds__(256) void trpw_k(const float* __restrict__ pw,
                                              float* __restrict__ wt)
{
    int g = blockIdx.x * 256 + threadIdx.x;      // 0..131071
    int k = g >> 10;
    int j = g & 1023;
    wt[g] = pw[(size_t)j * 384 + k];
}

// ------------------------- GRU recurrence (1 block / sample) ---------------
// Step-invariant weights live in REGISTERS across the whole t-loop:
//   pwh[128]  : post_w h-column for output tid          (all 1024 threads)
//   whr[128]  : whh column for gate-output tid          (threads 0..383)
// Per step: matvecs = register FMAs + LDS-broadcast h; only the
// data-dependent z-gather + ai/fpost rows touch global memory.
__global__ __launch_bounds__(1024, 1) void gru_k(const float* __restrict__ wihT,
    const float* __restrict__ whhT, const float* __restrict__ bhh,
    const float* __restrict__ ai, const float* __restrict__ fpost,
    const float* __restrict__ pwhT, float* __restrict__ out)
{
    float* out_post = out + 1048576;
    float* out_h    = out + 2097152;
    float* out_z    = out + 2228224;
    int b    = blockIdx.x;
    int tid  = threadIdx.x;
    int lane = tid & 31;                  // position within a 32-wide chunk
    int chnk = tid >> 5;                  // chunk id 0..31
    __shared__ __align__(16) float h[128];
    __shared__ float gi[384], gh[384];
    __shared__ int idx[32];

    // ---- one-time coalesced weight preload into registers -----------------
    float pwh[128];
#pragma unroll
    for (int k = 0; k < 128; k++) pwh[k] = pwhT[(size_t)k * 1024 + tid];
    float whr[128];
    if (tid < 384) {
#pragma unroll
        for (int k = 0; k < 128; k++) whr[k] = whhT[(size_t)k * 384 + tid];
    }
    float bh = (tid < 384) ? bhh[tid] : 0.f;
    if (tid < 128) h[tid] = 0.f;
    __syncthreads();

    for (int t = 0; t < 64; t++) {
        int n = b * 64 + t;
        float fp = fpost[(size_t)n * 1024 + tid];       // early independent load
        if (tid < 384) {
            float a = ai[(size_t)n * 384 + tid];
            if (t > 0) {
#pragma unroll
                for (int c = 0; c < 32; c++)
                    a += wihT[(size_t)(c * 32 + idx[c]) * 384 + tid];  // coalesced
            }
            gi[tid] = a;
            float a2 = bh;
#pragma unroll
            for (int k = 0; k < 128; k += 4) {
                float4 hv = *(const float4*)(h + k);               // LDS broadcast
                a2 += whr[k]*hv.x + whr[k+1]*hv.y + whr[k+2]*hv.z + whr[k+3]*hv.w;
            }
            gh[tid] = a2;
        }
        __syncthreads();                                    // B1
        if (tid < 128) {
            float r  = sigm_f(gi[tid] + gh[tid]);
            float u  = sigm_f(gi[128 + tid] + gh[128 + tid]);
            float nn = tanhf(gi[256 + tid] + r * gh[256 + tid]);
            float hn = (1.f - u) * nn + u * h[tid];
            h[tid] = hn;
            out_h[(size_t)n * 128 + tid] = hn;
        }
        __syncthreads();                                    // B2
        float a3 = fp;
#pragma unroll
        for (int k = 0; k < 128; k += 4) {
            float4 hv = *(const float4*)(h + k);                   // LDS broadcast
            a3 += pwh[k]*hv.x + pwh[k+1]*hv.y + pwh[k+2]*hv.z + pwh[k+3]*hv.w;
        }
        out_post[(size_t)n * 1024 + tid] = a3;
        // ---- argmax over the 32 lanes of this chunk (shfl butterfly) ------
        // first-max semantics: on equal value keep the smaller index.
        float bv = a3; int bi = lane;
#pragma unroll
        for (int off = 16; off > 0; off >>= 1) {
            float ov = __shfl_xor(bv, off, 32);
            int   oi = __shfl_xor(bi, off, 32);
            if (ov > bv || (ov == bv && oi < bi)) { bv = ov; bi = oi; }
        }
        out_z[(size_t)n * 1024 + tid] = (lane == bi) ? 1.f : 0.f;
        if (lane == 0) idx[chnk] = bi;
        __syncthreads();                                    // B3 (idx for t+1)
    }
}

// ---------------------------------------------------------------------------
extern "C" void kernel_launch(void* const* d_in, const int* in_sizes, int n_in,
                              void* d_out, int out_size, void* d_ws, size_t ws_size,
                              hipStream_t stream)
{
    const float* states  = (const float*)d_in[0];
    const float* actions = (const float*)d_in[1];
    const float* c1w = (const float*)d_in[2];  const float* c1b = (const float*)d_in[3];
    const float* l1g = (const float*)d_in[4];  const float* l1b = (const float*)d_in[5];
    const float* c2w = (const float*)d_in[6];  const float* c2b = (const float*)d_in[7];
    const float* l2g = (const float*)d_in[8];  const float* l2b = (const float*)d_in[9];
    const float* c3w = (const float*)d_in[10]; const float* c3b = (const float*)d_in[11];
    const float* l3g = (const float*)d_in[12]; const float* l3b = (const float*)d_in[13];
    const float* c4w = (const float*)d_in[14]; const float* c4b = (const float*)d_in[15];
    const float* l4g = (const float*)d_in[16]; const float* l4b = (const float*)d_in[17];
    const float* fcw = (const float*)d_in[18]; const float* fcb = (const float*)d_in[19];
    const float* wih = (const float*)d_in[20]; const float* whh = (const float*)d_in[21];
    const float* bih = (const float*)d_in[22]; const float* bhh = (const float*)d_in[23];
    const float* prw = (const float*)d_in[24]; const float* prb = (const float*)d_in[25];
    const float* pw  = (const float*)d_in[26]; const float* pb  = (const float*)d_in[27];

    float* out = (float*)d_out;
    float* ws  = (float*)d_ws;

    // ---- adaptive chunking: largest S whose footprint fits ws_size --------
    // footprint = (S*49152 + fixed 3,325,952) floats
    size_t S = 64;
    {
        const size_t cands[4] = {1024, 512, 256, 128};
        for (int i = 0; i < 4; i++) {
            size_t need = (cands[i] * 49152ull + 3325952ull) * 4ull;
            if (need <= ws_size) { S = cands[i]; break; }
        }
    }
    int C = (int)(1024 / S);

    float* bufA  = ws;                       // S*32768
    float* bufB  = bufA + S * 32768;         // S*16384
    float* feats = bufB + S * 16384;         //   262,144
    float* fpost = feats + 262144;           // 1,048,576
    float* aibuf = fpost + 1048576;          //   393,216
    float* wihT  = aibuf + 393216;           //   393,216
    float* fcwT  = wihT + 393216;            // 1,048,576
    float* whhT  = fcwT + 1048576;           //    49,152
    float* pwhT  = whhT + 49152;             //   131,072

    trfc_k<<<dim3(128, 8), 256, 0, stream>>>(fcw, fcwT);

    for (int cc = 0; cc < C; cc++) {
        size_t n0 = (size_t)cc * S;
        conv1_k<<<dim3((unsigned)S, 4), 256, 0, stream>>>(states + n0 * 12288, c1w, c1b, bufA);
        ln_fuse_k<<<(unsigned)S, 256, 0, stream>>>(bufA, l1g, l1b, 32768);
        conv2_r<<<(unsigned)S, 256, 0, stream>>>(bufA, c2w, c2b, bufB);
        ln_fuse_k<<<(unsigned)S, 256, 0, stream>>>(bufB, l2g, l2b, 16384);
        conv3_r<<<(unsigned)S, 256, 0, stream>>>(bufB, c3w, c3b, bufA);
        ln_fuse_k<<<(unsigned)S, 256, 0, stream>>>(bufA, l3g, l3b, 8192);
        conv4_f<<<(unsigned)S, 256, 0, stream>>>(bufA, c4w, c4b, l4g, l4b, bufB);
        fc_k2<<<(unsigned)(S / 8), 256, 0, stream>>>(bufB, fcwT, fcb, feats + n0 * 256);
    }

    fpost_k<<<256, 256, 0, stream>>>(feats, pw, pb, fpost);
    ai_k<<<dim3(1024, 3), 128, 0, stream>>>(actions, wih, bih, aibuf);
    tr_k<<<1536, 256, 0, stream>>>(wih, wihT);
    tr2_k<<<192, 256, 0, stream>>>(whh, whhT);
    trpw_k<<<512, 256, 0, stream>>>(pw, pwhT);

    gru_k<<<16, 1024, 0, stream>>>(wihT, whhT, bhh, aibuf, fpost, pwhT, out);
    prior_k<<<256, 256, 0, stream>>>(out + 2097152, prw, prb, out);
}